// Round 8
// baseline (503.415 us; speedup 1.0000x reference)
//
#include <hip/hip_runtime.h>
#include <stdint.h>

typedef __attribute__((ext_vector_type(8))) short short8;
typedef __attribute__((ext_vector_type(4))) float f32x4;
typedef __attribute__((ext_vector_type(4))) unsigned short us4;

#define DI __device__ __forceinline__

static constexpr int Dm = 1024;   // hidden dim
static constexpr int Sm = 4096;   // latent tokens
static constexpr int Em = 160;    // encoder tokens
static constexpr int Hm = 16;     // heads

// workspace layout (bytes)
static constexpr size_t OFF_HSB  = 0;           // hs bf16 [8*4096][1024]; reused as attn-out bf16
static constexpr size_t OFF_WT   = 67108864;    // 4x Wt bf16 [1024][1024] (transposed: [N][K])
static constexpr size_t OFF_QB   = 75497472;    // Q bf16 [8*4096][1024]
static constexpr size_t OFF_KB   = 142606336;   // K bf16 [8*160][1024]
static constexpr size_t OFF_VT   = 147849216;   // V^T bf16 [8][16][64][192]
static constexpr size_t OFF_EHSB = 150994944;   // ehs bf16 [8*160][1024]

DI unsigned short f2b(float f) {
  union { float f; unsigned u; } x; x.f = f;
  unsigned r = x.u + 0x7fffu + ((x.u >> 16) & 1u);
  return (unsigned short)(r >> 16);
}

DI void gl_lds16(const void* g, void* l) {
  __builtin_amdgcn_global_load_lds(
      (const __attribute__((address_space(1))) unsigned int*)g,
      (__attribute__((address_space(3))) unsigned int*)l, 16, 0, 0);
}

// inline-asm LDS read: opaque to the compiler's LDS-DMA alias analysis, so it
// cannot insert a conservative s_waitcnt vmcnt(0) before it (the per-phase
// full-drain that killed R6/R7). Ordering vs gl_lds is OUR responsibility:
// vmcnt(4) gates at p4/p8 + barriers (race-free schedule below).
DI short8 lds_rd128(unsigned off) {
  float4 d;
  asm volatile("ds_read_b128 %0, %1" : "=&v"(d) : "v"(off));
  union { float4 f; short8 s; } u; u.f = d; return u.s;
}

#define S_BARRIER __builtin_amdgcn_s_barrier()
#define LGKM0 do { asm volatile("s_waitcnt lgkmcnt(0)" ::: "memory"); __builtin_amdgcn_sched_barrier(0); } while (0)
#define VMCNT(n) asm volatile("s_waitcnt vmcnt(" #n ")" ::: "memory")

// ---------------- fp32 -> bf16 convert (vectorized, grid-stride) ----------------
__global__ void k_cvt(const float* __restrict__ in, unsigned short* __restrict__ out, int n4) {
  int stride = gridDim.x * blockDim.x;
  for (int i = blockIdx.x * blockDim.x + threadIdx.x; i < n4; i += stride) {
    float4 v = ((const float4*)in)[i];
    us4 o = { f2b(v.x), f2b(v.y), f2b(v.z), f2b(v.w) };
    *(us4*)(out + (size_t)i * 4) = o;
  }
}

// ---------------- W [K][N] fp32 -> Wt [N][K] bf16 (tiled transpose) ----------------
__global__ void k_wtrans(const float* __restrict__ W0, const float* __restrict__ W1,
                         const float* __restrict__ W2, const float* __restrict__ W3,
                         unsigned short* __restrict__ Wt) {
  __shared__ float t[32][33];
  const float* W = (blockIdx.z == 0) ? W0 : (blockIdx.z == 1) ? W1 : (blockIdx.z == 2) ? W2 : W3;
  unsigned short* o = Wt + (size_t)blockIdx.z * 1048576;
  int tx = threadIdx.x, ty = threadIdx.y;
  int n = blockIdx.x * 32 + tx;
  int k0 = blockIdx.y * 32;
  #pragma unroll
  for (int j = ty; j < 32; j += 8) t[j][tx] = W[(size_t)(k0 + j) * 1024 + n];
  __syncthreads();
  #pragma unroll
  for (int j = ty; j < 32; j += 8)
    o[(size_t)(blockIdx.x * 32 + j) * 1024 + k0 + tx] = f2b(t[tx][j]);
}

// ---------------- 256x256-tile 8-phase counted-vmcnt bf16 GEMM (race-free) ----------------
// C[M,1024] = A[M,1024] @ Bt[1024,1024]^T.  512 thr = 8 waves (2M x 4N), per-wave
// 128x64 out. BK=64, LDS 128KB (A/B x 2 dbuf). Iter v: t=2v from dbuf0 (p1-p4),
// t+1 from dbuf1 (p5-p8). Reads/phase: p1 af(mh0)+bf0(nh0), p2 bf1(nh1),
// p3 af(mh1), p4 NONE (reuse bf0), p5-p8 mirror on dbuf1. Quad order 00,01,11,10.
// Stage slots (each >= 1 barrier after last read of its region, lands >= 4 phases later):
//   p1:A0(t+1)->d1  p2:A1(t+1)->d1  p3:B0(t+2)->d0  p4:B1(t+2)->d0
//   p5:A0(t+2)->d0  p6:A1(t+2)->d0  p7:B0(t+3)->d1  p8:B1(t+3)->d1
// vmcnt(4) (loads; 2 newest stages) at p4-end (dbuf1=t+1 complete for p5) and
// p8-end (dbuf0=t+2 complete for next p1). Last iter: p4-end drains to 0.
// MODE 0: bf16 C via LDS-staged coalesced epilogue. MODE 1: fp32 C + bias + resid.
template<int MODE>
__global__ __launch_bounds__(512, 2) void k_gemm256(const unsigned short* __restrict__ A,
                                                    const unsigned short* __restrict__ Bt,
                                                    void* __restrict__ Cout,
                                                    const float* __restrict__ bias,
                                                    const float* __restrict__ resid) {
  __shared__ __align__(16) char smem[131072];   // A: [2 dbuf][256][128B] @0 ; B: same @65536
  const int tid = threadIdx.x;
  const int lane = tid & 63;
  const int l15 = lane & 15;
  const int g = lane >> 4;
  const int wv = tid >> 6;
  const int wr = wv >> 2;           // 0..1 (M half)
  const int wcn = wv & 3;           // 0..3 (N quarter)
  const int bid = blockIdx.x;
  const int m0 = (((bid >> 5) << 3) + (bid & 7)) * 256;
  const int n0 = ((bid >> 3) & 3) * 256;

  typedef __attribute__((address_space(3))) char c3;
  const unsigned lds0 = (unsigned)(size_t)(c3*)smem;
  unsigned swz[2];
  swz[0] = (unsigned)((g * 16) ^ ((l15 & 7) << 4));
  swz[1] = (unsigned)((64 + g * 16) ^ ((l15 & 7) << 4));
  const unsigned baseA = lds0 + (unsigned)((wr * 128 + l15) * 128);
  const unsigned baseB = lds0 + 65536u + (unsigned)((wcn * 64 + l15) * 128);

  f32x4 acc[8][4];
  #pragma unroll
  for (int i = 0; i < 8; ++i)
    #pragma unroll
    for (int j = 0; j < 4; ++j) acc[i][j] = (f32x4){0.f, 0.f, 0.f, 0.f};

  // stage one 16KB half-tile (128 rows x 64 cols) of A (isB=0) or B (isB=1),
  // K-step tk, half hf, into dbuf db. 2x gl_lds(16B)/thread. Pre-swizzled src.
  auto STG = [&](const unsigned short* G, int isB, int db, int hf, int tk) {
    int mn0 = isB ? n0 : m0;
    #pragma unroll
    for (int p = 0; p < 2; ++p) {
      int chl = p * 512 + tid;
      int rih = chl >> 3, j = chl & 7;
      int sj = (j ^ (rih & 7)) * 8;
      gl_lds16(G + (size_t)(mn0 + hf * 128 + rih) * 1024 + tk * 64 + sj,
               smem + isB * 65536 + db * 32768 + (hf * 1024 + chl) * 16);
    }
  };
  auto LDA = [&](short8 (&af)[2][4], int db, int mh) {
    #pragma unroll
    for (int kk = 0; kk < 2; ++kk)
      #pragma unroll
      for (int mt = 0; mt < 4; ++mt)
        af[kk][mt] = lds_rd128(baseA + (unsigned)(db * 32768 + mh * 8192 + mt * 2048) + swz[kk]);
  };
  auto LDB = [&](short8 (&bf)[2][2], int db, int nh) {
    #pragma unroll
    for (int kk = 0; kk < 2; ++kk)
      #pragma unroll
      for (int nt = 0; nt < 2; ++nt)
        bf[kk][nt] = lds_rd128(baseB + (unsigned)(db * 32768 + nh * 4096 + nt * 2048) + swz[kk]);
  };
  auto MM = [&](short8 (&af)[2][4], short8 (&bf)[2][2], int mh, int nh) {
    __builtin_amdgcn_s_setprio(1);
    #pragma unroll
    for (int kk = 0; kk < 2; ++kk)
      #pragma unroll
      for (int mt = 0; mt < 4; ++mt)
        #pragma unroll
        for (int nt = 0; nt < 2; ++nt)
          acc[mh * 4 + mt][nh * 2 + nt] = __builtin_amdgcn_mfma_f32_16x16x32_bf16(
              af[kk][mt], bf[kk][nt], acc[mh * 4 + mt][nh * 2 + nt], 0, 0, 0);
    __builtin_amdgcn_s_setprio(0);
    __builtin_amdgcn_sched_barrier(0);
  };

  // prologue: t0 fully -> dbuf0 (oldest 8 loads), t1 B-halves -> dbuf1.
  STG(A, 0, 0, 0, 0); STG(A, 0, 0, 1, 0); STG(Bt, 1, 0, 0, 0); STG(Bt, 1, 0, 1, 0);
  STG(Bt, 1, 1, 0, 1); STG(Bt, 1, 1, 1, 1);
  VMCNT(4);            // t0 landed (B(1) may remain in flight)
  S_BARRIER;

  short8 af[2][4], bf0[2][2], bf1[2][2];
  #pragma unroll 1
  for (int v = 0; v < 8; ++v) {
    const int t = 2 * v;
    const bool more = (v < 7);
    // p1
    LDA(af, 0, 0); LDB(bf0, 0, 0);
    STG(A, 0, 1, 0, t + 1);
    S_BARRIER; LGKM0;
    MM(af, bf0, 0, 0);
    S_BARRIER;
    // p2
    LDB(bf1, 0, 1);
    STG(A, 0, 1, 1, t + 1);
    S_BARRIER; LGKM0;
    MM(af, bf1, 0, 1);
    S_BARRIER;
    // p3
    LDA(af, 0, 1);
    if (more) STG(Bt, 1, 0, 0, t + 2);
    S_BARRIER; LGKM0;
    MM(af, bf1, 1, 1);
    S_BARRIER;
    // p4 (no ds_reads; reuse bf0 from p1)
    if (more) STG(Bt, 1, 0, 1, t + 2);
    S_BARRIER;
    MM(af, bf0, 1, 0);
    if (more) { VMCNT(4); } else { VMCNT(0); }
    S_BARRIER;
    // p5
    LDA(af, 1, 0); LDB(bf0, 1, 0);
    if (more) STG(A, 0, 0, 0, t + 2);
    S_BARRIER; LGKM0;
    MM(af, bf0, 0, 0);
    S_BARRIER;
    // p6
    LDB(bf1, 1, 1);
    if (more) STG(A, 0, 0, 1, t + 2);
    S_BARRIER; LGKM0;
    MM(af, bf1, 0, 1);
    S_BARRIER;
    // p7
    LDA(af, 1, 1);
    if (more) STG(Bt, 1, 1, 0, t + 3);
    S_BARRIER; LGKM0;
    MM(af, bf1, 1, 1);
    S_BARRIER;
    // p8 (no ds_reads; reuse bf0 from p5)
    if (more) STG(Bt, 1, 1, 1, t + 3);
    S_BARRIER;
    MM(af, bf0, 1, 0);
    VMCNT(4);
    S_BARRIER;
  }

  __syncthreads();
  if (MODE == 0) {
    // LDS-staged coalesced bf16 epilogue (kills 2x write amplification)
    unsigned short* Cl = (unsigned short*)smem;
    #pragma unroll
    for (int m = 0; m < 8; ++m)
      #pragma unroll
      for (int n = 0; n < 4; ++n)
        #pragma unroll
        for (int r = 0; r < 4; ++r)
          Cl[(wr * 128 + m * 16 + 4 * g + r) * 256 + wcn * 64 + n * 16 + l15] = f2b(acc[m][n][r]);
    __syncthreads();
    #pragma unroll
    for (int j = 0; j < 16; ++j) {
      int ch = j * 512 + tid;
      int row = ch >> 5, sl = ch & 31;
      *(short8*)((unsigned short*)Cout + (size_t)(m0 + row) * 1024 + n0 + sl * 8) =
          *(const short8*)(Cl + row * 256 + sl * 8);
    }
  } else {
    #pragma unroll
    for (int m = 0; m < 8; ++m)
      #pragma unroll
      for (int n = 0; n < 4; ++n)
        #pragma unroll
        for (int r = 0; r < 4; ++r) {
          size_t row = (size_t)(m0 + wr * 128 + m * 16 + 4 * g + r);
          int col = n0 + wcn * 64 + n * 16 + l15;
          size_t idx = row * 1024 + col;
          ((float*)Cout)[idx] = acc[m][n][r] + bias[col] + resid[idx];
        }
  }
}

// ---------------- fused K+V projection GEMM (128x128 tile, small) ----------------
// A = ehs bf16 [1280][1024]; z=0: K -> kb [1280][1024] bf16;
// z=1: V -> written TRANSPOSED into vt [bc][h][d][192].
__global__ __launch_bounds__(256, 2) void k_gemm_kv(const unsigned short* __restrict__ A,
                                                    const unsigned short* __restrict__ Wt,
                                                    unsigned short* __restrict__ kb,
                                                    unsigned short* __restrict__ vt) {
  __shared__ __align__(16) char smem[32768];
  char* As = smem;
  char* Bs = smem + 16384;
  const int tid = threadIdx.x;
  const int lane = tid & 63;
  const int l15 = lane & 15;
  const int g = lane >> 4;
  const int wv = tid >> 6;
  const int wr = wv >> 1, wc = wv & 1;
  const int m0 = blockIdx.x * 128, n0 = blockIdx.y * 128;
  const int z = blockIdx.z;
  const unsigned short* Bt = Wt + (size_t)(1 + z) * 1048576;

  f32x4 acc[4][4];
  #pragma unroll
  for (int i = 0; i < 4; ++i)
    #pragma unroll
    for (int j = 0; j < 4; ++j) acc[i][j] = (f32x4){0.f, 0.f, 0.f, 0.f};

  for (int t = 0; t < 16; ++t) {
    __syncthreads();
    #pragma unroll
    for (int is = 0; is < 4; ++is) {
      int ch = is * 256 + tid;
      int row = ch >> 3, j = ch & 7;
      int sj = (j ^ (row & 7)) * 8;
      gl_lds16(A  + (size_t)(m0 + row) * 1024 + t * 64 + sj, As + ch * 16);
      gl_lds16(Bt + (size_t)(n0 + row) * 1024 + t * 64 + sj, Bs + ch * 16);
    }
    __syncthreads();
    short8 af[2][4], bf[2][4];
    #pragma unroll
    for (int kk = 0; kk < 2; ++kk)
      #pragma unroll
      for (int mt = 0; mt < 4; ++mt) {
        af[kk][mt] = *(const short8*)(As + (wr * 64 + mt * 16 + l15) * 128 + ((kk * 64 + g * 16) ^ ((l15 & 7) << 4)));
        bf[kk][mt] = *(const short8*)(Bs + (wc * 64 + mt * 16 + l15) * 128 + ((kk * 64 + g * 16) ^ ((l15 & 7) << 4)));
      }
    #pragma unroll
    for (int kk = 0; kk < 2; ++kk)
      #pragma unroll
      for (int mt = 0; mt < 4; ++mt)
        #pragma unroll
        for (int nt = 0; nt < 4; ++nt)
          acc[mt][nt] = __builtin_amdgcn_mfma_f32_16x16x32_bf16(af[kk][mt], bf[kk][nt], acc[mt][nt], 0, 0, 0);
  }

  #pragma unroll
  for (int mt = 0; mt < 4; ++mt)
    #pragma unroll
    for (int nt = 0; nt < 4; ++nt)
      #pragma unroll
      for (int r = 0; r < 4; ++r) {
        int row = m0 + wr * 64 + mt * 16 + 4 * g + r;   // [0,1280)
        int col = n0 + wc * 64 + nt * 16 + l15;         // [0,1024)
        unsigned short hv = f2b(acc[mt][nt][r]);
        if (z == 0) {
          kb[(size_t)row * 1024 + col] = hv;
        } else {
          int bc = row / 160, e = row - bc * 160;       // h = col>>6, d = col&63
          vt[((size_t)(bc * 16 + (col >> 6)) * 64 + (col & 63)) * 192 + e] = hv;
        }
      }
}

// ---------------- fused decomposing attention (v3) ----------------
// grid (S/64, H, B=2); block 256 = 4 waves; wave w = component c (bc = c*2 + b).
// No Q/K/V LDS staging: MFMA fragments loaded directly from global (L2-resident).
// Component weight wp applied AFTER PV (scalar per row) -> one barrier per strip.
__global__ __launch_bounds__(256, 2) void k_attn(const unsigned short* __restrict__ Qb,
                                                 const unsigned short* __restrict__ Kb,
                                                 const unsigned short* __restrict__ Vt,
                                                 unsigned short* __restrict__ AOb) {
  __shared__ __align__(16) char smem[22528];
  float* pooled = (float*)(smem + 21504);   // [4][16][4] f32
  const int tid = threadIdx.x, lane = tid & 63, wv = tid >> 6;
  const int g = lane >> 4, l15 = lane & 15;
  const int s0 = blockIdx.x * 64;
  const int h = blockIdx.y;
  const int b = blockIdx.z;
  const int bc = wv * 2 + b;
  const float scale = 0.125f;

  const unsigned short* Qp = Qb + ((size_t)bc * Sm + s0) * Dm + h * 64;
  const unsigned short* Kp = Kb + (size_t)bc * Em * Dm + h * 64;
  const unsigned short* Vp = Vt + ((size_t)bc * Hm + h) * (64 * 192);
  unsigned short* Op = AOb + ((size_t)bc * Sm + s0) * Dm + h * 64;
  char* Pw = smem + wv * 5376;              // [16 rows][336B]

  #pragma unroll 1
  for (int st = 0; st < 4; ++st) {
    // ---- QK^T: fragments direct from global ----
    short8 qf[2];
    #pragma unroll
    for (int kk = 0; kk < 2; ++kk)
      qf[kk] = *(const short8*)(Qp + (size_t)(st * 16 + l15) * Dm + kk * 32 + g * 8);
    f32x4 sc[10];
    #pragma unroll
    for (int et = 0; et < 10; ++et) {
      sc[et] = (f32x4){0.f, 0.f, 0.f, 0.f};
      #pragma unroll
      for (int kk = 0; kk < 2; ++kk) {
        short8 kf = *(const short8*)(Kp + (size_t)(et * 16 + l15) * Dm + kk * 32 + g * 8);
        sc[et] = __builtin_amdgcn_mfma_f32_16x16x32_bf16(qf[kk], kf, sc[et], 0, 0, 0);
      }
    }
    // ---- pooled mean + row softmax numerators (rows s = st*16 + 4g + r) ----
    float rs4[4];
    #pragma unroll
    for (int r = 0; r < 4; ++r) {
      float v = 0.f;
      #pragma unroll
      for (int et = 0; et < 10; ++et) v += sc[et][r];
      v += __shfl_xor(v, 1); v += __shfl_xor(v, 2); v += __shfl_xor(v, 4); v += __shfl_xor(v, 8);
      if (l15 == 0) pooled[(st * 16 + 4 * g + r) * 4 + wv] = v * (scale / 160.f);
      float mx = sc[0][r];
      #pragma unroll
      for (int et = 1; et < 10; ++et) mx = fmaxf(mx, sc[et][r]);
      mx = fmaxf(mx, __shfl_xor(mx, 1)); mx = fmaxf(mx, __shfl_xor(mx, 2));
      mx = fmaxf(mx, __shfl_xor(mx, 4)); mx = fmaxf(mx, __shfl_xor(mx, 8));
      float rs = 0.f;
      #pragma unroll
      for (int et = 0; et < 10; ++et) {
        float p = __expf((sc[et][r] - mx) * scale);
        rs += p;
        *(unsigned short*)(Pw + (4 * g + r) * 336 + (et * 16 + l15) * 2) = f2b(p);
      }
      rs += __shfl_xor(rs, 1); rs += __shfl_xor(rs, 2); rs += __shfl_xor(rs, 4); rs += __shfl_xor(rs, 8);
      rs4[r] = rs;
    }
    // ---- PV (P from per-wave LDS transpose, V^T direct from global) ----
    f32x4 oa[4];
    #pragma unroll
    for (int dt = 0; dt < 4; ++dt) oa[dt] = (f32x4){0.f, 0.f, 0.f, 0.f};
    #pragma unroll
    for (int k5 = 0; k5 < 5; ++k5) {
      short8 pf = *(const short8*)(Pw + l15 * 336 + k5 * 64 + g * 16);
      #pragma unroll
      for (int dt = 0; dt < 4; ++dt) {
        short8 vf = *(const short8*)(Vp + (size_t)(dt * 16 + l15) * 192 + k5 * 32 + g * 8);
        oa[dt] = __builtin_amdgcn_mfma_f32_16x16x32_bf16(pf, vf, oa[dt], 0, 0, 0);
      }
    }
    __syncthreads();   // all waves have written pooled[st]
    // ---- component softmax rescale + store ----
    #pragma unroll
    for (int r = 0; r < 4; ++r) {
      float4 pl = *(const float4*)&pooled[(st * 16 + 4 * g + r) * 4];
      float m3 = fmaxf(fmaxf(pl.x, pl.y), fmaxf(pl.z, pl.w));
      float ssum = __expf(pl.x - m3) + __expf(pl.y - m3) + __expf(pl.z - m3) + __expf(pl.w - m3);
      float mine = (wv == 0) ? pl.x : (wv == 1) ? pl.y : (wv == 2) ? pl.z : pl.w;
      float srw = __expf(mine - m3) / (ssum * rs4[r]);
      #pragma unroll
      for (int dt = 0; dt < 4; ++dt)
        Op[(size_t)(st * 16 + 4 * g + r) * Dm + dt * 16 + l15] = f2b(oa[dt][r] * srw);
    }
  }
}

extern "C" void kernel_launch(void* const* d_in, const int* in_sizes, int n_in,
                              void* d_out, int out_size, void* d_ws, size_t ws_size,
                              hipStream_t stream) {
  const float* hs  = (const float*)d_in[0];
  const float* ehs = (const float*)d_in[1];
  const float* Wq  = (const float*)d_in[2];
  const float* Wk  = (const float*)d_in[3];
  const float* Wv  = (const float*)d_in[4];
  const float* Wo  = (const float*)d_in[5];
  const float* bo  = (const float*)d_in[6];
  char* ws = (char*)d_ws;
  unsigned short* hsb = (unsigned short*)(ws + OFF_HSB);   // hs bf16; reused as attn-out bf16
  unsigned short* wt  = (unsigned short*)(ws + OFF_WT);
  unsigned short* qb  = (unsigned short*)(ws + OFF_QB);
  unsigned short* kb  = (unsigned short*)(ws + OFF_KB);
  unsigned short* vt  = (unsigned short*)(ws + OFF_VT);
  unsigned short* eb  = (unsigned short*)(ws + OFF_EHSB);

  hipLaunchKernelGGL(k_cvt, dim3(1280), dim3(256), 0, stream, ehs, eb, 8 * 160 * 1024 / 4);
  hipLaunchKernelGGL(k_wtrans, dim3(32, 32, 4), dim3(32, 8), 0, stream, Wq, Wk, Wv, Wo, wt);
  hipLaunchKernelGGL(k_gemm_kv, dim3(10, 8, 2), dim3(256), 0, stream, eb, wt, kb, vt);
  hipLaunchKernelGGL(k_cvt, dim3(2048), dim3(256), 0, stream, hs, hsb, 8 * 4096 * 1024 / 4);
  hipLaunchKernelGGL((k_gemm256<0>), dim3(512), dim3(512), 0, stream, hsb, wt, (void*)qb,
                     (const float*)nullptr, (const float*)nullptr);
  hipLaunchKernelGGL(k_attn, dim3(64, 16, 2), dim3(256), 0, stream, qb, kb, vt, hsb);
  hipLaunchKernelGGL((k_gemm256<1>), dim3(512), dim3(512), 0, stream, hsb, wt + 3 * 1048576, d_out, bo, hs);
}

// Round 9
// 327.941 us; speedup vs baseline: 1.5351x; 1.5351x over previous
//
#include <hip/hip_runtime.h>
#include <stdint.h>

typedef __attribute__((ext_vector_type(8))) short short8;
typedef __attribute__((ext_vector_type(4))) float f32x4;
typedef __attribute__((ext_vector_type(4))) unsigned short us4;

#define DI __device__ __forceinline__

static constexpr int Dm = 1024;   // hidden dim
static constexpr int Sm = 4096;   // latent tokens
static constexpr int Em = 160;    // encoder tokens
static constexpr int Hm = 16;     // heads

// workspace layout (bytes)
static constexpr size_t OFF_HSB  = 0;           // hs bf16 [8*4096][1024]; reused as attn-out bf16
static constexpr size_t OFF_WT   = 67108864;    // 4x Wt bf16 [1024][1024] (transposed: [N][K])
static constexpr size_t OFF_QB   = 75497472;    // Q bf16 [8*4096][1024]
static constexpr size_t OFF_KB   = 142606336;   // K bf16 [8*160][1024]
static constexpr size_t OFF_VT   = 147849216;   // V^T bf16 [8][16][64][192]
static constexpr size_t OFF_EHSB = 150994944;   // ehs bf16 [8*160][1024]

DI unsigned short f2b(float f) {
  union { float f; unsigned u; } x; x.f = f;
  unsigned r = x.u + 0x7fffu + ((x.u >> 16) & 1u);
  return (unsigned short)(r >> 16);
}

DI void gl_lds16(const void* g, void* l) {
  __builtin_amdgcn_global_load_lds(
      (const __attribute__((address_space(1))) unsigned int*)g,
      (__attribute__((address_space(3))) unsigned int*)l, 16, 0, 0);
}

// ---------------- prep0: W transpose+cvt (4096 blocks) || ehs cvt (1280 blocks) ----------------
__global__ void k_prep0(const float* __restrict__ ehs, unsigned short* __restrict__ eb,
                        const float* __restrict__ W0, const float* __restrict__ W1,
                        const float* __restrict__ W2, const float* __restrict__ W3,
                        unsigned short* __restrict__ Wt) {
  __shared__ float t[32][33];
  const int bid = blockIdx.x, tid = threadIdx.x;
  if (bid < 4096) {
    const int bz = bid >> 10, rest = bid & 1023, by = rest >> 5, bx = rest & 31;
    const float* W = (bz == 0) ? W0 : (bz == 1) ? W1 : (bz == 2) ? W2 : W3;
    unsigned short* o = Wt + (size_t)bz * 1048576;
    const int tx = tid & 31, ty = tid >> 5;
    const int n = bx * 32 + tx, k0 = by * 32;
    #pragma unroll
    for (int j = ty; j < 32; j += 8) t[j][tx] = W[(size_t)(k0 + j) * 1024 + n];
    __syncthreads();
    #pragma unroll
    for (int j = ty; j < 32; j += 8)
      o[(size_t)(bx * 32 + j) * 1024 + k0 + tx] = f2b(t[tx][j]);
  } else {
    // ehs cvt: 8*160*1024/4 = 327680 float4 = 1280 blocks x 256 exactly
    const int i = (bid - 4096) * 256 + tid;
    float4 v = ((const float4*)ehs)[i];
    us4 o = { f2b(v.x), f2b(v.y), f2b(v.z), f2b(v.w) };
    *(us4*)(eb + (size_t)i * 4) = o;
  }
}

// ---------------- prep1: K+V projection GEMM (160 blocks) || hs cvt (2048 blocks) ----------------
// kv: A = ehs bf16 [1280][1024]; z=0: K -> kb bf16 [1280][1024];
//     z=1: V -> TRANSPOSED into vt [bc][h][d][192].
// cvt blocks (bid>=160) convert hs fp32 -> hsb bf16 (BW-bound, hides the kv GEMM).
__global__ __launch_bounds__(256, 2) void k_prep1(const float* __restrict__ hs,
                                                  unsigned short* __restrict__ hsb,
                                                  const unsigned short* __restrict__ eb,
                                                  const unsigned short* __restrict__ Wt,
                                                  unsigned short* __restrict__ kb,
                                                  unsigned short* __restrict__ vt) {
  __shared__ __align__(16) char smem[32768];
  const int bid = blockIdx.x, tid = threadIdx.x;
  if (bid >= 160) {
    // hs cvt: n4 = 8*4096*1024/4 = 8388608 float4; 2048 blocks, 16 iters each
    const int stride = 2048 * 256;
    for (int i = (bid - 160) * 256 + tid; i < 8388608; i += stride) {
      float4 v = ((const float4*)hs)[i];
      us4 o = { f2b(v.x), f2b(v.y), f2b(v.z), f2b(v.w) };
      *(us4*)(hsb + (size_t)i * 4) = o;
    }
    return;
  }
  char* As = smem;
  char* Bs = smem + 16384;
  const int lane = tid & 63;
  const int l15 = lane & 15;
  const int g = lane >> 4;
  const int wv = tid >> 6;
  const int wr = wv >> 1, wc = wv & 1;
  const int z = bid / 80, rr = bid - z * 80;
  const int m0 = (rr % 10) * 128, n0 = (rr / 10) * 128;
  const unsigned short* Bt = Wt + (size_t)(1 + z) * 1048576;

  f32x4 acc[4][4];
  #pragma unroll
  for (int i = 0; i < 4; ++i)
    #pragma unroll
    for (int j = 0; j < 4; ++j) acc[i][j] = (f32x4){0.f, 0.f, 0.f, 0.f};

  for (int t = 0; t < 16; ++t) {
    __syncthreads();
    #pragma unroll
    for (int is = 0; is < 4; ++is) {
      int ch = is * 256 + tid;
      int row = ch >> 3, j = ch & 7;
      int sj = (j ^ (row & 7)) * 8;
      gl_lds16(eb + (size_t)(m0 + row) * 1024 + t * 64 + sj, As + ch * 16);
      gl_lds16(Bt + (size_t)(n0 + row) * 1024 + t * 64 + sj, Bs + ch * 16);
    }
    __syncthreads();
    short8 af[2][4], bf[2][4];
    #pragma unroll
    for (int kk = 0; kk < 2; ++kk)
      #pragma unroll
      for (int mt = 0; mt < 4; ++mt) {
        af[kk][mt] = *(const short8*)(As + (wr * 64 + mt * 16 + l15) * 128 + ((kk * 64 + g * 16) ^ ((l15 & 7) << 4)));
        bf[kk][mt] = *(const short8*)(Bs + (wc * 64 + mt * 16 + l15) * 128 + ((kk * 64 + g * 16) ^ ((l15 & 7) << 4)));
      }
    #pragma unroll
    for (int kk = 0; kk < 2; ++kk)
      #pragma unroll
      for (int mt = 0; mt < 4; ++mt)
        #pragma unroll
        for (int nt = 0; nt < 4; ++nt)
          acc[mt][nt] = __builtin_amdgcn_mfma_f32_16x16x32_bf16(af[kk][mt], bf[kk][nt], acc[mt][nt], 0, 0, 0);
  }

  #pragma unroll
  for (int mt = 0; mt < 4; ++mt)
    #pragma unroll
    for (int nt = 0; nt < 4; ++nt)
      #pragma unroll
      for (int r = 0; r < 4; ++r) {
        int row = m0 + wr * 64 + mt * 16 + 4 * g + r;   // [0,1280)
        int col = n0 + wc * 64 + nt * 16 + l15;         // [0,1024)
        unsigned short hv = f2b(acc[mt][nt][r]);
        if (z == 0) {
          kb[(size_t)row * 1024 + col] = hv;
        } else {
          int bc = row / 160, e = row - bc * 160;       // h = col>>6, d = col&63
          vt[((size_t)(bc * 16 + (col >> 6)) * 64 + (col & 63)) * 192 + e] = hv;
        }
      }
}

// ---------------- 128x128-tile bf16 GEMM (m97-class, known-good R3 body) ----------------
// C[M,1024] = A[M,1024] @ Bt[1024,1024]^T. BK=64, gl_lds(16B), XOR-swizzled LDS,
// 2-barrier loop, 4 waves. 1D grid co-residency decode (R5-proven, FETCH 331->97MB):
//   xcd = bid&7; n0 = ((bid>>3)&7)*128; m0 = ((bid>>6)*8 + xcd)*128
// -> per-XCD concurrent window ~ few A M-panels x all 8 N-tiles; A+B ~ L2-fit.
// MODE 0: bf16 C via LDS-staged coalesced epilogue (write amp 132->64MB).
// MODE 1: fp32 C + bias[n] + resid[m][n] direct (64B/16-lane segments, no amp).
template<int MODE>
__global__ __launch_bounds__(256, 2) void k_gemm128(const unsigned short* __restrict__ A,
                                                    const unsigned short* __restrict__ Bt,
                                                    void* __restrict__ Cout,
                                                    const float* __restrict__ bias,
                                                    const float* __restrict__ resid) {
  __shared__ __align__(16) char smem[32768];
  char* As = smem;
  char* Bs = smem + 16384;
  const int tid = threadIdx.x;
  const int lane = tid & 63;
  const int l15 = lane & 15;
  const int g = lane >> 4;
  const int wv = tid >> 6;
  const int wr = wv >> 1, wc = wv & 1;
  const int bid = blockIdx.x;
  const int m0 = ((bid >> 6) * 8 + (bid & 7)) * 128;
  const int n0 = ((bid >> 3) & 7) * 128;

  f32x4 acc[4][4];
  #pragma unroll
  for (int i = 0; i < 4; ++i)
    #pragma unroll
    for (int j = 0; j < 4; ++j) acc[i][j] = (f32x4){0.f, 0.f, 0.f, 0.f};

  for (int t = 0; t < 16; ++t) {
    __syncthreads();
    #pragma unroll
    for (int is = 0; is < 4; ++is) {
      int ch = is * 256 + tid;
      int row = ch >> 3, j = ch & 7;
      int sj = (j ^ (row & 7)) * 8;
      gl_lds16(A  + (size_t)(m0 + row) * 1024 + t * 64 + sj, As + ch * 16);
      gl_lds16(Bt + (size_t)(n0 + row) * 1024 + t * 64 + sj, Bs + ch * 16);
    }
    __syncthreads();
    short8 af[2][4], bf[2][4];
    #pragma unroll
    for (int kk = 0; kk < 2; ++kk)
      #pragma unroll
      for (int mt = 0; mt < 4; ++mt) {
        af[kk][mt] = *(const short8*)(As + (wr * 64 + mt * 16 + l15) * 128 + ((kk * 64 + g * 16) ^ ((l15 & 7) << 4)));
        bf[kk][mt] = *(const short8*)(Bs + (wc * 64 + mt * 16 + l15) * 128 + ((kk * 64 + g * 16) ^ ((l15 & 7) << 4)));
      }
    #pragma unroll
    for (int kk = 0; kk < 2; ++kk)
      #pragma unroll
      for (int mt = 0; mt < 4; ++mt)
        #pragma unroll
        for (int nt = 0; nt < 4; ++nt)
          acc[mt][nt] = __builtin_amdgcn_mfma_f32_16x16x32_bf16(af[kk][mt], bf[kk][nt], acc[mt][nt], 0, 0, 0);
  }

  if (MODE == 0) {
    // LDS-staged coalesced bf16 epilogue: Cl[128][128] bf16 = 32KB (reuses As/Bs)
    __syncthreads();
    unsigned short* Cl = (unsigned short*)smem;
    #pragma unroll
    for (int mt = 0; mt < 4; ++mt)
      #pragma unroll
      for (int nt = 0; nt < 4; ++nt)
        #pragma unroll
        for (int r = 0; r < 4; ++r)
          Cl[(wr * 64 + mt * 16 + 4 * g + r) * 128 + wc * 64 + nt * 16 + l15] = f2b(acc[mt][nt][r]);
    __syncthreads();
    #pragma unroll
    for (int j = 0; j < 8; ++j) {
      int ch = j * 256 + tid;
      int row = ch >> 4, sl = ch & 15;
      *(short8*)((unsigned short*)Cout + (size_t)(m0 + row) * 1024 + n0 + sl * 8) =
          *(const short8*)(Cl + row * 128 + sl * 8);
    }
  } else {
    #pragma unroll
    for (int mt = 0; mt < 4; ++mt)
      #pragma unroll
      for (int nt = 0; nt < 4; ++nt)
        #pragma unroll
        for (int r = 0; r < 4; ++r) {
          size_t row = (size_t)(m0 + wr * 64 + mt * 16 + 4 * g + r);
          int col = n0 + wc * 64 + nt * 16 + l15;
          size_t idx = row * 1024 + col;
          ((float*)Cout)[idx] = acc[mt][nt][r] + bias[col] + resid[idx];
        }
  }
}

// ---------------- fused decomposing attention (v3) ----------------
// grid (S/64, H, B=2); block 256 = 4 waves; wave w = component c (bc = c*2 + b).
// No Q/K/V LDS staging: MFMA fragments loaded directly from global (L2-resident).
// Component weight wp applied AFTER PV (scalar per row) -> one barrier per strip.
__global__ __launch_bounds__(256, 2) void k_attn(const unsigned short* __restrict__ Qb,
                                                 const unsigned short* __restrict__ Kb,
                                                 const unsigned short* __restrict__ Vt,
                                                 unsigned short* __restrict__ AOb) {
  __shared__ __align__(16) char smem[22528];
  float* pooled = (float*)(smem + 21504);   // [4][16][4] f32
  const int tid = threadIdx.x, lane = tid & 63, wv = tid >> 6;
  const int g = lane >> 4, l15 = lane & 15;
  const int s0 = blockIdx.x * 64;
  const int h = blockIdx.y;
  const int b = blockIdx.z;
  const int bc = wv * 2 + b;
  const float scale = 0.125f;

  const unsigned short* Qp = Qb + ((size_t)bc * Sm + s0) * Dm + h * 64;
  const unsigned short* Kp = Kb + (size_t)bc * Em * Dm + h * 64;
  const unsigned short* Vp = Vt + ((size_t)bc * Hm + h) * (64 * 192);
  unsigned short* Op = AOb + ((size_t)bc * Sm + s0) * Dm + h * 64;
  char* Pw = smem + wv * 5376;              // [16 rows][336B]

  #pragma unroll 1
  for (int st = 0; st < 4; ++st) {
    // ---- QK^T: fragments direct from global ----
    short8 qf[2];
    #pragma unroll
    for (int kk = 0; kk < 2; ++kk)
      qf[kk] = *(const short8*)(Qp + (size_t)(st * 16 + l15) * Dm + kk * 32 + g * 8);
    f32x4 sc[10];
    #pragma unroll
    for (int et = 0; et < 10; ++et) {
      sc[et] = (f32x4){0.f, 0.f, 0.f, 0.f};
      #pragma unroll
      for (int kk = 0; kk < 2; ++kk) {
        short8 kf = *(const short8*)(Kp + (size_t)(et * 16 + l15) * Dm + kk * 32 + g * 8);
        sc[et] = __builtin_amdgcn_mfma_f32_16x16x32_bf16(qf[kk], kf, sc[et], 0, 0, 0);
      }
    }
    // ---- pooled mean + row softmax numerators (rows s = st*16 + 4g + r) ----
    float rs4[4];
    #pragma unroll
    for (int r = 0; r < 4; ++r) {
      float v = 0.f;
      #pragma unroll
      for (int et = 0; et < 10; ++et) v += sc[et][r];
      v += __shfl_xor(v, 1); v += __shfl_xor(v, 2); v += __shfl_xor(v, 4); v += __shfl_xor(v, 8);
      if (l15 == 0) pooled[(st * 16 + 4 * g + r) * 4 + wv] = v * (scale / 160.f);
      float mx = sc[0][r];
      #pragma unroll
      for (int et = 1; et < 10; ++et) mx = fmaxf(mx, sc[et][r]);
      mx = fmaxf(mx, __shfl_xor(mx, 1)); mx = fmaxf(mx, __shfl_xor(mx, 2));
      mx = fmaxf(mx, __shfl_xor(mx, 4)); mx = fmaxf(mx, __shfl_xor(mx, 8));
      float rs = 0.f;
      #pragma unroll
      for (int et = 0; et < 10; ++et) {
        float p = __expf((sc[et][r] - mx) * scale);
        rs += p;
        *(unsigned short*)(Pw + (4 * g + r) * 336 + (et * 16 + l15) * 2) = f2b(p);
      }
      rs += __shfl_xor(rs, 1); rs += __shfl_xor(rs, 2); rs += __shfl_xor(rs, 4); rs += __shfl_xor(rs, 8);
      rs4[r] = rs;
    }
    // ---- PV (P from per-wave LDS transpose, V^T direct from global) ----
    f32x4 oa[4];
    #pragma unroll
    for (int dt = 0; dt < 4; ++dt) oa[dt] = (f32x4){0.f, 0.f, 0.f, 0.f};
    #pragma unroll
    for (int k5 = 0; k5 < 5; ++k5) {
      short8 pf = *(const short8*)(Pw + l15 * 336 + k5 * 64 + g * 16);
      #pragma unroll
      for (int dt = 0; dt < 4; ++dt) {
        short8 vf = *(const short8*)(Vp + (size_t)(dt * 16 + l15) * 192 + k5 * 32 + g * 8);
        oa[dt] = __builtin_amdgcn_mfma_f32_16x16x32_bf16(pf, vf, oa[dt], 0, 0, 0);
      }
    }
    __syncthreads();   // all waves have written pooled[st]
    // ---- component softmax rescale + store ----
    #pragma unroll
    for (int r = 0; r < 4; ++r) {
      float4 pl = *(const float4*)&pooled[(st * 16 + 4 * g + r) * 4];
      float m3 = fmaxf(fmaxf(pl.x, pl.y), fmaxf(pl.z, pl.w));
      float ssum = __expf(pl.x - m3) + __expf(pl.y - m3) + __expf(pl.z - m3) + __expf(pl.w - m3);
      float mine = (wv == 0) ? pl.x : (wv == 1) ? pl.y : (wv == 2) ? pl.z : pl.w;
      float srw = __expf(mine - m3) / (ssum * rs4[r]);
      #pragma unroll
      for (int dt = 0; dt < 4; ++dt)
        Op[(size_t)(st * 16 + 4 * g + r) * Dm + dt * 16 + l15] = f2b(oa[dt][r] * srw);
    }
  }
}

extern "C" void kernel_launch(void* const* d_in, const int* in_sizes, int n_in,
                              void* d_out, int out_size, void* d_ws, size_t ws_size,
                              hipStream_t stream) {
  const float* hs  = (const float*)d_in[0];
  const float* ehs = (const float*)d_in[1];
  const float* Wq  = (const float*)d_in[2];
  const float* Wk  = (const float*)d_in[3];
  const float* Wv  = (const float*)d_in[4];
  const float* Wo  = (const float*)d_in[5];
  const float* bo  = (const float*)d_in[6];
  char* ws = (char*)d_ws;
  unsigned short* hsb = (unsigned short*)(ws + OFF_HSB);   // hs bf16; reused as attn-out bf16
  unsigned short* wt  = (unsigned short*)(ws + OFF_WT);
  unsigned short* qb  = (unsigned short*)(ws + OFF_QB);
  unsigned short* kb  = (unsigned short*)(ws + OFF_KB);
  unsigned short* vt  = (unsigned short*)(ws + OFF_VT);
  unsigned short* eb  = (unsigned short*)(ws + OFF_EHSB);

  hipLaunchKernelGGL(k_prep0, dim3(4096 + 1280), dim3(256), 0, stream, ehs, eb, Wq, Wk, Wv, Wo, wt);
  hipLaunchKernelGGL(k_prep1, dim3(160 + 2048), dim3(256), 0, stream, hs, hsb, eb, wt, kb, vt);
  hipLaunchKernelGGL((k_gemm128<0>), dim3(2048), dim3(256), 0, stream, hsb, wt, (void*)qb,
                     (const float*)nullptr, (const float*)nullptr);
  hipLaunchKernelGGL(k_attn, dim3(64, 16, 2), dim3(256), 0, stream, qb, kb, vt, hsb);
  hipLaunchKernelGGL((k_gemm128<1>), dim3(2048), dim3(256), 0, stream, hsb, wt + 3 * 1048576, d_out, bo, hs);
}